// Round 6
// baseline (80.924 us; speedup 1.0000x reference)
//
#include <hip/hip_runtime.h>
#include <hip/hip_bf16.h>
#include <cstdint>

#define SEQ   2048
#define HD    64
#define NBH   32
#define QBLK  128           // per block (8 waves x 16 rows)
#define KVBLK 64
#define NQB   (SEQ / QBLK)  // 16
#define LDK   72            // padded LDS stride (shorts)
// scale = 1/sqrt(64) * log2(e)  (softmax done in exp2 domain)
#define QSC   0.18033688011112042f
#define THR   11.0f         // defer-max threshold (log2 domain)

typedef __attribute__((ext_vector_type(8))) short short8;
typedef __attribute__((ext_vector_type(4))) float floatx4;

#if __has_builtin(__builtin_amdgcn_exp2f)
#define EXP2(x) __builtin_amdgcn_exp2f(x)
#else
#define EXP2(x) __expf((x) * 0.69314718055994531f)
#endif

static __device__ __forceinline__ short f2bf(float f) {
    union { float f; unsigned u; } x; x.f = f;
    return (short)((x.u + 0x7fffu + ((x.u >> 16) & 1u)) >> 16);  // RNE
}
static __device__ __forceinline__ unsigned pkbf(float a, float b) {
    __hip_bfloat162 h = __float22bfloat162_rn(make_float2(a, b));
    union { __hip_bfloat162 h; unsigned u; } c; c.h = h; return c.u;
}

// ---------------- prep kernels (proven) ----------------

__global__ __launch_bounds__(256)
void conv_k_kernel(const float* __restrict__ K, short* __restrict__ Kb) {
    size_t i = ((size_t)blockIdx.x * 256 + threadIdx.x) * 8;
    float4 a = *(const float4*)(K + i);
    float4 b = *(const float4*)(K + i + 4);
    union { unsigned u[4]; short8 s; } cv;
    cv.u[0] = pkbf(a.x, a.y); cv.u[1] = pkbf(a.z, a.w);
    cv.u[2] = pkbf(b.x, b.y); cv.u[3] = pkbf(b.z, b.w);
    *(short8*)(Kb + i) = cv.s;
}

__global__ __launch_bounds__(256)
void trans_v_kernel(const float* __restrict__ V, short* __restrict__ Vt) {
    __shared__ __align__(16) short Vs[64][72];
    const int tid = threadIdx.x;
    const int bh = blockIdx.x >> 5;
    const int t  = blockIdx.x & 31;
    const float* src = V + ((size_t)bh * SEQ + (size_t)t * 64) * HD;
    #pragma unroll
    for (int i = 0; i < 4; ++i) {
        int idx = i * 256 + tid;
        int r = idx >> 4; int c = (idx & 15) * 4;
        float4 f = *(const float4*)(src + r * HD + c);
        Vs[c + 0][r] = f2bf(f.x); Vs[c + 1][r] = f2bf(f.y);
        Vs[c + 2][r] = f2bf(f.z); Vs[c + 3][r] = f2bf(f.w);
    }
    __syncthreads();
    short* dst = Vt + (size_t)bh * HD * SEQ + t * 64;
    #pragma unroll
    for (int i = 0; i < 2; ++i) {
        int idx = i * 256 + tid;
        int d = idx >> 3; int j = idx & 7;
        short8 v = *(const short8*)&Vs[d][j * 8];
        *(short8*)(dst + (size_t)d * SEQ + j * 8) = v;
    }
}

// ---------------- main attention kernel (v6) ----------------
// 8 waves x 16 q-rows = 128 q/block; KVBLK=64; reg-prefetch staging;
// defer-max; setprio; wave-uniform skip of fully-masked tiles.

__global__ __launch_bounds__(512, 4)
void fa_fwd_v6(const float* __restrict__ Q, const short* __restrict__ Kg,
               const short* __restrict__ Vtg, float* __restrict__ O)
{
    const int tid  = threadIdx.x;
    const int lane = tid & 63;
    const int wv   = tid >> 6;        // wave 0..7
    const int l15  = lane & 15;
    const int lg   = lane >> 4;
    const int dofs = lg * 8;

    const int bh = blockIdx.x & (NBH - 1);
    const int qb = (NQB - 1) - (blockIdx.x >> 5);   // heavy blocks first
    const int qrow0 = qb * QBLK + wv * 16;          // wave's first q row
    const int qmax_w = qrow0 + 15;
    const int T = 2 * qb + 2;                       // KV tiles of 64

    const float* Qp = Q   + (size_t)bh * SEQ * HD;
    const short* Kp = Kg  + (size_t)bh * SEQ * HD;
    const short* Vp = Vtg + (size_t)bh * HD * SEQ;
    float*       Op = O   + (size_t)bh * SEQ * HD;

    __shared__ __align__(16) short K_lds[KVBLK][LDK];   // [kv][d]
    __shared__ __align__(16) short Vt_lds[HD][LDK];     // [d][kv]
    __shared__ __align__(16) short Pl[8][16][LDK];      // per-wave P tile

    // staging: 512 x 16B chunks per tile; exactly 1 K-chunk + 1 V-chunk/thread
    const int srow = tid >> 3, scol = (tid & 7) * 8;
    const int kgo = srow * HD + scol;                   // K global offset (shorts)
    const int vgo = srow * SEQ + scol;                  // Vt global offset

    // ---- Q fragments from fp32 global, scale folded, packed bf16 ----
    short8 qfrag[2];
    {
        const float* src = Qp + (size_t)(qrow0 + l15) * HD + dofs;
        union { unsigned u[4]; short8 s; } cv;
        float4 f0 = *(const float4*)(src);
        float4 f1 = *(const float4*)(src + 4);
        cv.u[0] = pkbf(f0.x * QSC, f0.y * QSC); cv.u[1] = pkbf(f0.z * QSC, f0.w * QSC);
        cv.u[2] = pkbf(f1.x * QSC, f1.y * QSC); cv.u[3] = pkbf(f1.z * QSC, f1.w * QSC);
        qfrag[0] = cv.s;
        f0 = *(const float4*)(src + 32);
        f1 = *(const float4*)(src + 36);
        cv.u[0] = pkbf(f0.x * QSC, f0.y * QSC); cv.u[1] = pkbf(f0.z * QSC, f0.w * QSC);
        cv.u[2] = pkbf(f1.x * QSC, f1.y * QSC); cv.u[3] = pkbf(f1.z * QSC, f1.w * QSC);
        qfrag[1] = cv.s;
    }

    // ---- prologue: prefetch tile 0 into registers ----
    short8 kr = *(const short8*)(Kp + kgo);
    short8 vr = *(const short8*)(Vp + vgo);

    floatx4 o_acc[4];
    #pragma unroll
    for (int dt = 0; dt < 4; ++dt)
        #pragma unroll
        for (int e = 0; e < 4; ++e) o_acc[dt][e] = 0.0f;
    float m_r[4], l_r[4];
    #pragma unroll
    for (int r = 0; r < 4; ++r) { m_r[r] = -1e30f; l_r[r] = 0.0f; }

    for (int t = 0; t < T; ++t) {
        __syncthreads();   // previous iteration's readers done with LDS
        *(short8*)&K_lds[srow][scol]  = kr;
        *(short8*)&Vt_lds[srow][scol] = vr;
        __syncthreads();   // tile t visible to all waves

        if (t + 1 < T) {
            kr = *(const short8*)(Kp + (size_t)(t + 1) * KVBLK * HD + kgo);
            vr = *(const short8*)(Vp + (t + 1) * KVBLK + vgo);
        }

        // wave-uniform: skip tiles entirely above this wave's q range
        if (t * KVBLK > qmax_w) continue;   // barriers at loop top stay uniform

        // ---- S = (Q*scale) K^T ----
        floatx4 s_acc[4];
        __builtin_amdgcn_s_setprio(1);
        #pragma unroll
        for (int n = 0; n < 4; ++n) {
            const short8 k0 = *(const short8*)&K_lds[n * 16 + l15][dofs];
            const short8 k1 = *(const short8*)&K_lds[n * 16 + l15][dofs + 32];
            floatx4 acc = {0.0f, 0.0f, 0.0f, 0.0f};
            acc = __builtin_amdgcn_mfma_f32_16x16x32_bf16(qfrag[0], k0, acc, 0, 0, 0);
            acc = __builtin_amdgcn_mfma_f32_16x16x32_bf16(qfrag[1], k1, acc, 0, 0, 0);
            s_acc[n] = acc;
        }
        __builtin_amdgcn_s_setprio(0);

        // ---- causal mask (tiles overlapping the diagonal of this wave) ----
        if (t * KVBLK + KVBLK - 1 > qrow0) {
            #pragma unroll
            for (int n = 0; n < 4; ++n)
                #pragma unroll
                for (int r = 0; r < 4; ++r) {
                    int kc = t * KVBLK + n * 16 + l15;   // global k
                    int qr = qrow0 + lg * 4 + r;         // global q
                    if (kc > qr) s_acc[n][r] = -1e30f;
                }
        }

        // ---- online softmax (exp2 domain, defer-max) ----
        #pragma unroll
        for (int r = 0; r < 4; ++r) {
            float rmax = fmaxf(fmaxf(s_acc[0][r], s_acc[1][r]),
                               fmaxf(s_acc[2][r], s_acc[3][r]));
            rmax = fmaxf(rmax, __shfl_xor(rmax, 1));
            rmax = fmaxf(rmax, __shfl_xor(rmax, 2));
            rmax = fmaxf(rmax, __shfl_xor(rmax, 4));
            rmax = fmaxf(rmax, __shfl_xor(rmax, 8));
            if (rmax > m_r[r] + THR) {       // uniform within 16-lane group
                float alpha = EXP2(m_r[r] - rmax);
                m_r[r] = rmax;
                l_r[r] *= alpha;
                #pragma unroll
                for (int dt = 0; dt < 4; ++dt) o_acc[dt][r] *= alpha;
            }
            const float mm = m_r[r];
            float p0 = EXP2(s_acc[0][r] - mm);
            float p1 = EXP2(s_acc[1][r] - mm);
            float p2 = EXP2(s_acc[2][r] - mm);
            float p3 = EXP2(s_acc[3][r] - mm);
            l_r[r] += (p0 + p1) + (p2 + p3);
            unsigned ua = pkbf(p0, p1), ub = pkbf(p2, p3);
            short* prow = &Pl[wv][lg * 4 + r][l15];
            prow[0]  = (short)(ua & 0xffff);
            prow[16] = (short)(ua >> 16);
            prow[32] = (short)(ub & 0xffff);
            prow[48] = (short)(ub >> 16);
        }
        // wave-local LDS RAW: wait for this wave's ds_writes
        asm volatile("s_waitcnt lgkmcnt(0)" ::: "memory");

        // ---- O += P V ----
        const short8 p0 = *(const short8*)&Pl[wv][l15][dofs];
        const short8 p1 = *(const short8*)&Pl[wv][l15][dofs + 32];
        __builtin_amdgcn_s_setprio(1);
        #pragma unroll
        for (int dt = 0; dt < 4; ++dt) {
            const short8 v0 = *(const short8*)&Vt_lds[dt * 16 + l15][dofs];
            const short8 v1 = *(const short8*)&Vt_lds[dt * 16 + l15][dofs + 32];
            o_acc[dt] = __builtin_amdgcn_mfma_f32_16x16x32_bf16(p0, v0, o_acc[dt], 0, 0, 0);
            o_acc[dt] = __builtin_amdgcn_mfma_f32_16x16x32_bf16(p1, v1, o_acc[dt], 0, 0, 0);
        }
        __builtin_amdgcn_s_setprio(0);
    }

    // ---- finalize: reduce l across the 16-lane group, divide, store ----
    #pragma unroll
    for (int r = 0; r < 4; ++r) {
        float l = l_r[r];
        l += __shfl_xor(l, 1);
        l += __shfl_xor(l, 2);
        l += __shfl_xor(l, 4);
        l += __shfl_xor(l, 8);
        l_r[r] = 1.0f / l;
    }
    #pragma unroll
    for (int dt = 0; dt < 4; ++dt)
        #pragma unroll
        for (int r = 0; r < 4; ++r) {
            int row = qrow0 + lg * 4 + r;
            Op[(size_t)row * HD + dt * 16 + l15] = o_acc[dt][r] * l_r[r];
        }
}

// ---------------- fallback (round-1 kernel, proven) if ws too small ----------------

__global__ __launch_bounds__(256, 2)
void fa_fwd_v1(const float* __restrict__ Q, const float* __restrict__ K,
               const float* __restrict__ V, float* __restrict__ O)
{
    const int tid  = threadIdx.x;
    const int lane = tid & 63;
    const int wv   = tid >> 6;
    const int l15  = lane & 15;
    const int lg   = lane >> 4;
    const int dofs = lg * 8;
    const int bh = blockIdx.x & (NBH - 1);
    const int qi = 31 - (blockIdx.x >> 5);
    const size_t base = (size_t)bh * SEQ * HD;
    const float* Qp = Q + base; const float* Kp = K + base;
    const float* Vp = V + base; float* Op = O + base;
    const int qbase = qi * 64;
    __shared__ __align__(16) short K_lds[64][72];
    __shared__ __align__(16) short Vt_lds[HD][72];
    __shared__ __align__(16) short P_lds[4][16][72];
    short8 qfrag[2];
    {
        const float* src = Qp + (size_t)(qbase + wv * 16 + l15) * HD + dofs;
        #pragma unroll
        for (int c = 0; c < 2; ++c) {
            float4 f0 = *(const float4*)(src + 32 * c);
            float4 f1 = *(const float4*)(src + 32 * c + 4);
            short8 tt;
            tt[0] = f2bf(f0.x * 0.125f); tt[1] = f2bf(f0.y * 0.125f);
            tt[2] = f2bf(f0.z * 0.125f); tt[3] = f2bf(f0.w * 0.125f);
            tt[4] = f2bf(f1.x * 0.125f); tt[5] = f2bf(f1.y * 0.125f);
            tt[6] = f2bf(f1.z * 0.125f); tt[7] = f2bf(f1.w * 0.125f);
            qfrag[c] = tt;
        }
    }
    floatx4 o_acc[4];
    #pragma unroll
    for (int dt = 0; dt < 4; ++dt)
        #pragma unroll
        for (int e = 0; e < 4; ++e) o_acc[dt][e] = 0.0f;
    float m_r[4], l_r[4];
    #pragma unroll
    for (int r = 0; r < 4; ++r) { m_r[r] = -1e30f; l_r[r] = 0.0f; }
    for (int t = 0; t <= qi; ++t) {
        __syncthreads();
        {
            const float4* ks = (const float4*)(Kp + (size_t)t * 64 * HD);
            const float4* vs = (const float4*)(Vp + (size_t)t * 64 * HD);
            #pragma unroll
            for (int j = 0; j < 4; ++j) {
                int idx = j * 256 + tid;
                int row = idx >> 4;
                int col = (idx & 15) << 2;
                float4 kf = ks[idx];
                K_lds[row][col + 0] = f2bf(kf.x); K_lds[row][col + 1] = f2bf(kf.y);
                K_lds[row][col + 2] = f2bf(kf.z); K_lds[row][col + 3] = f2bf(kf.w);
                float4 vf = vs[idx];
                Vt_lds[col + 0][row] = f2bf(vf.x); Vt_lds[col + 1][row] = f2bf(vf.y);
                Vt_lds[col + 2][row] = f2bf(vf.z); Vt_lds[col + 3][row] = f2bf(vf.w);
            }
        }
        __syncthreads();
        floatx4 s_acc[4];
        #pragma unroll
        for (int n = 0; n < 4; ++n) {
            const short8 k0 = *(const short8*)&K_lds[n * 16 + l15][dofs];
            const short8 k1 = *(const short8*)&K_lds[n * 16 + l15][dofs + 32];
            floatx4 acc = {0.0f, 0.0f, 0.0f, 0.0f};
            acc = __builtin_amdgcn_mfma_f32_16x16x32_bf16(qfrag[0], k0, acc, 0, 0, 0);
            acc = __builtin_amdgcn_mfma_f32_16x16x32_bf16(qfrag[1], k1, acc, 0, 0, 0);
            s_acc[n] = acc;
        }
        if (t == qi) {
            #pragma unroll
            for (int n = 0; n < 4; ++n)
                #pragma unroll
                for (int r = 0; r < 4; ++r) {
                    int qr = wv * 16 + lg * 4 + r;
                    int kc = n * 16 + l15;
                    if (kc > qr) s_acc[n][r] = -1e30f;
                }
        }
        #pragma unroll
        for (int r = 0; r < 4; ++r) {
            float rmax = fmaxf(fmaxf(s_acc[0][r], s_acc[1][r]),
                               fmaxf(s_acc[2][r], s_acc[3][r]));
            rmax = fmaxf(rmax, __shfl_xor(rmax, 1));
            rmax = fmaxf(rmax, __shfl_xor(rmax, 2));
            rmax = fmaxf(rmax, __shfl_xor(rmax, 4));
            rmax = fmaxf(rmax, __shfl_xor(rmax, 8));
            float mnew  = fmaxf(m_r[r], rmax);
            float alpha = __expf(m_r[r] - mnew);
            m_r[r] = mnew;
            l_r[r] *= alpha;
            #pragma unroll
            for (int dt = 0; dt < 4; ++dt) o_acc[dt][r] *= alpha;
            #pragma unroll
            for (int n = 0; n < 4; ++n) {
                float p = __expf(s_acc[n][r] - mnew);
                l_r[r] += p;
                P_lds[wv][lg * 4 + r][n * 16 + l15] = f2bf(p);
            }
        }
        asm volatile("s_waitcnt lgkmcnt(0)" ::: "memory");
        const short8 p0 = *(const short8*)&P_lds[wv][l15][dofs];
        const short8 p1 = *(const short8*)&P_lds[wv][l15][dofs + 32];
        #pragma unroll
        for (int dt = 0; dt < 4; ++dt) {
            const short8 v0 = *(const short8*)&Vt_lds[dt * 16 + l15][dofs];
            const short8 v1 = *(const short8*)&Vt_lds[dt * 16 + l15][dofs + 32];
            o_acc[dt] = __builtin_amdgcn_mfma_f32_16x16x32_bf16(p0, v0, o_acc[dt], 0, 0, 0);
            o_acc[dt] = __builtin_amdgcn_mfma_f32_16x16x32_bf16(p1, v1, o_acc[dt], 0, 0, 0);
        }
    }
    #pragma unroll
    for (int r = 0; r < 4; ++r) {
        float l = l_r[r];
        l += __shfl_xor(l, 1);
        l += __shfl_xor(l, 2);
        l += __shfl_xor(l, 4);
        l += __shfl_xor(l, 8);
        l_r[r] = 1.0f / l;
    }
    #pragma unroll
    for (int dt = 0; dt < 4; ++dt)
        #pragma unroll
        for (int r = 0; r < 4; ++r) {
            int row = qbase + wv * 16 + lg * 4 + r;
            Op[(size_t)row * HD + dt * 16 + l15] = o_acc[dt][r] * l_r[r];
        }
}

extern "C" void kernel_launch(void* const* d_in, const int* in_sizes, int n_in,
                              void* d_out, int out_size, void* d_ws, size_t ws_size,
                              hipStream_t stream) {
    const float* q = (const float*)d_in[0];
    const float* k = (const float*)d_in[1];
    const float* v = (const float*)d_in[2];
    float* o = (float*)d_out;
    (void)in_sizes; (void)n_in; (void)out_size;

    const size_t elems = (size_t)NBH * SEQ * HD;
    const size_t need  = 2 * elems * sizeof(short);
    if (ws_size >= need) {
        short* kb = (short*)d_ws;
        short* vt = kb + elems;
        conv_k_kernel<<<dim3(elems / (256 * 8)), dim3(256), 0, stream>>>(k, kb);
        trans_v_kernel<<<dim3(NBH * 32), dim3(256), 0, stream>>>(v, vt);
        fa_fwd_v6<<<dim3(NBH * NQB), dim3(512), 0, stream>>>(q, kb, vt, o);
    } else {
        fa_fwd_v1<<<dim3(NBH * 32), dim3(256), 0, stream>>>(q, k, v, o);
    }
}

// Round 7
// 57.614 us; speedup vs baseline: 1.4046x; 1.4046x over previous
//
#include <hip/hip_runtime.h>
#include <hip/hip_bf16.h>
#include <cstdint>

#define SEQ   2048
#define HD    64
#define NBH   32
#define QBLK  64
#define KVBLK 64
#define NQT   (SEQ / QBLK)  // 32
#define LDK   72            // padded LDS stride (shorts): 144B rows
// scale = 1/sqrt(64) * log2(e)  (softmax in exp2 domain)
#define QSC   0.18033688011112042f
#define THR   11.0f         // defer-max threshold (log2 domain)

typedef __attribute__((ext_vector_type(8))) short short8;
typedef __attribute__((ext_vector_type(4))) float floatx4;
typedef __attribute__((ext_vector_type(2))) unsigned uint2v;

#if __has_builtin(__builtin_amdgcn_exp2f)
#define EXP2(x) __builtin_amdgcn_exp2f(x)
#else
#define EXP2(x) __expf((x) * 0.69314718055994531f)
#endif

static __device__ __forceinline__ short f2bf(float f) {
    union { float f; unsigned u; } x; x.f = f;
    return (short)((x.u + 0x7fffu + ((x.u >> 16) & 1u)) >> 16);  // RNE
}
static __device__ __forceinline__ unsigned pkbf(float a, float b) {
    __hip_bfloat162 h = __float22bfloat162_rn(make_float2(a, b));
    union { __hip_bfloat162 h; unsigned u; } c; c.h = h; return c.u;
}

// ---------------- prep kernels (proven) ----------------

__global__ __launch_bounds__(256)
void conv_k_kernel(const float* __restrict__ K, short* __restrict__ Kb) {
    size_t i = ((size_t)blockIdx.x * 256 + threadIdx.x) * 8;
    float4 a = *(const float4*)(K + i);
    float4 b = *(const float4*)(K + i + 4);
    union { unsigned u[4]; short8 s; } cv;
    cv.u[0] = pkbf(a.x, a.y); cv.u[1] = pkbf(a.z, a.w);
    cv.u[2] = pkbf(b.x, b.y); cv.u[3] = pkbf(b.z, b.w);
    *(short8*)(Kb + i) = cv.s;
}

__global__ __launch_bounds__(256)
void trans_v_kernel(const float* __restrict__ V, short* __restrict__ Vt) {
    __shared__ __align__(16) short Vs[64][72];
    const int tid = threadIdx.x;
    const int bh = blockIdx.x >> 5;
    const int t  = blockIdx.x & 31;
    const float* src = V + ((size_t)bh * SEQ + (size_t)t * 64) * HD;
    #pragma unroll
    for (int i = 0; i < 4; ++i) {
        int idx = i * 256 + tid;
        int r = idx >> 4; int c = (idx & 15) * 4;
        float4 f = *(const float4*)(src + r * HD + c);
        Vs[c + 0][r] = f2bf(f.x); Vs[c + 1][r] = f2bf(f.y);
        Vs[c + 2][r] = f2bf(f.z); Vs[c + 3][r] = f2bf(f.w);
    }
    __syncthreads();
    short* dst = Vt + (size_t)bh * HD * SEQ + t * 64;
    #pragma unroll
    for (int i = 0; i < 2; ++i) {
        int idx = i * 256 + tid;
        int d = idx >> 3; int j = idx & 7;
        short8 v = *(const short8*)&Vs[d][j * 8];
        *(short8*)(dst + (size_t)d * SEQ + j * 8) = v;
    }
}

// ---------------- main attention kernel (v7) ----------------
// v4 geometry (4 waves x 16 q, KVBLK=64, reg-prefetch) +
// swapped QK^T (S^T: q=l15 lane-local softmax state) + packed b64 P writes +
// defer-max with rare-path rescale + double-buffered K/V, ONE barrier/tile.

__global__ __launch_bounds__(256, 4)
void fa_fwd_v7(const float* __restrict__ Q, const short* __restrict__ Kg,
               const short* __restrict__ Vtg, float* __restrict__ O)
{
    const int tid  = threadIdx.x;
    const int lane = tid & 63;
    const int wv   = tid >> 6;
    const int l15  = lane & 15;
    const int lg   = lane >> 4;
    const int lg4  = lg * 4;
    const int dofs = lg * 8;

    const int bh = blockIdx.x & (NBH - 1);
    const int qi = (NQT - 1) - (blockIdx.x >> 5);   // heavy tiles first
    const int qbase = qi * QBLK;

    const float* Qp = Q   + (size_t)bh * SEQ * HD;
    const short* Kp = Kg  + (size_t)bh * SEQ * HD;
    const short* Vp = Vtg + (size_t)bh * HD * SEQ;
    float*       Op = O   + (size_t)bh * SEQ * HD;

    __shared__ __align__(16) short K_lds[2][KVBLK][LDK];   // [buf][kv][d]
    __shared__ __align__(16) short Vt_lds[2][HD][LDK];     // [buf][d][kv]
    __shared__ __align__(16) short Pl[4][16][LDK];         // per-wave P [q][k]

    // staging geometry: 512 x 16B chunks per tile; 2 per thread for K, V each
    const int r0 = tid >> 3,         j0 = tid & 7;
    const int r1 = (tid + 256) >> 3, j1 = tid & 7;
    const int kg0 = r0 * HD + j0 * 8, kg1 = r1 * HD + j1 * 8;
    const int vg0 = r0 * SEQ + j0 * 8, vg1 = r1 * SEQ + j1 * 8;

    // ---- Q fragments (B-operand now; same per-lane layout), scale folded ----
    short8 qfrag[2];
    {
        const float* src = Qp + (size_t)(qbase + wv * 16 + l15) * HD + dofs;
        union { unsigned u[4]; short8 s; } cv;
        float4 f0 = *(const float4*)(src);
        float4 f1 = *(const float4*)(src + 4);
        cv.u[0] = pkbf(f0.x * QSC, f0.y * QSC); cv.u[1] = pkbf(f0.z * QSC, f0.w * QSC);
        cv.u[2] = pkbf(f1.x * QSC, f1.y * QSC); cv.u[3] = pkbf(f1.z * QSC, f1.w * QSC);
        qfrag[0] = cv.s;
        f0 = *(const float4*)(src + 32);
        f1 = *(const float4*)(src + 36);
        cv.u[0] = pkbf(f0.x * QSC, f0.y * QSC); cv.u[1] = pkbf(f0.z * QSC, f0.w * QSC);
        cv.u[2] = pkbf(f1.x * QSC, f1.y * QSC); cv.u[3] = pkbf(f1.z * QSC, f1.w * QSC);
        qfrag[1] = cv.s;
    }

    // ---- prologue: prefetch tile 0 into registers ----
    short8 krA = *(const short8*)(Kp + kg0);
    short8 krB = *(const short8*)(Kp + kg1);
    short8 vrA = *(const short8*)(Vp + vg0);
    short8 vrB = *(const short8*)(Vp + vg1);

    floatx4 o_acc[4];
    #pragma unroll
    for (int dt = 0; dt < 4; ++dt)
        #pragma unroll
        for (int e = 0; e < 4; ++e) o_acc[dt][e] = 0.0f;
    float m_s = -1e30f, l_s = 0.0f;   // per-lane state for q = l15

    for (int t = 0; t <= qi; ++t) {
        const int buf = t & 1;
        // ---- publish tile t (in regs) to LDS buf; other buf may still be read ----
        *(short8*)&K_lds[buf][r0][j0 * 8]  = krA;
        *(short8*)&K_lds[buf][r1][j1 * 8]  = krB;
        *(short8*)&Vt_lds[buf][r0][j0 * 8] = vrA;
        *(short8*)&Vt_lds[buf][r1][j1 * 8] = vrB;
        __syncthreads();   // buf published; prior buf's readers also done

        // ---- prefetch tile t+1; latency hidden under compute ----
        if (t < qi) {
            const short* ks = Kp + (size_t)(t + 1) * KVBLK * HD;
            const short* vs = Vp + (t + 1) * KVBLK;
            krA = *(const short8*)(ks + kg0);
            krB = *(const short8*)(ks + kg1);
            vrA = *(const short8*)(vs + vg0);
            vrB = *(const short8*)(vs + vg1);
        }

        // ---- S^T = K (Q*scale)^T : lane holds k=(lg4+r)+16n, q=l15 ----
        floatx4 s_acc[4];
        __builtin_amdgcn_s_setprio(1);
        #pragma unroll
        for (int n = 0; n < 4; ++n) {
            const short8 k0 = *(const short8*)&K_lds[buf][n * 16 + l15][dofs];
            const short8 k1 = *(const short8*)&K_lds[buf][n * 16 + l15][dofs + 32];
            floatx4 acc = {0.0f, 0.0f, 0.0f, 0.0f};
            acc = __builtin_amdgcn_mfma_f32_16x16x32_bf16(k0, qfrag[0], acc, 0, 0, 0);
            acc = __builtin_amdgcn_mfma_f32_16x16x32_bf16(k1, qfrag[1], acc, 0, 0, 0);
            s_acc[n] = acc;
        }
        __builtin_amdgcn_s_setprio(0);

        // ---- causal mask (diagonal tile only): klocal > qlocal ----
        if (t == qi) {
            const int qlocal = wv * 16 + l15;
            #pragma unroll
            for (int n = 0; n < 4; ++n)
                #pragma unroll
                for (int r = 0; r < 4; ++r)
                    if (n * 16 + lg4 + r > qlocal) s_acc[n][r] = -1e30f;
        }

        // ---- online softmax: in-lane tree + 2 cross-lg shfls ----
        float t0 = fmaxf(fmaxf(s_acc[0][0], s_acc[0][1]), fmaxf(s_acc[0][2], s_acc[0][3]));
        float t1 = fmaxf(fmaxf(s_acc[1][0], s_acc[1][1]), fmaxf(s_acc[1][2], s_acc[1][3]));
        float t2 = fmaxf(fmaxf(s_acc[2][0], s_acc[2][1]), fmaxf(s_acc[2][2], s_acc[2][3]));
        float t3 = fmaxf(fmaxf(s_acc[3][0], s_acc[3][1]), fmaxf(s_acc[3][2], s_acc[3][3]));
        float rmax = fmaxf(fmaxf(t0, t1), fmaxf(t2, t3));
        rmax = fmaxf(rmax, __shfl_xor(rmax, 16));
        rmax = fmaxf(rmax, __shfl_xor(rmax, 32));   // uniform across 4 lanes of q

        const bool trig = rmax > m_s + THR;
        if (trig) {                                  // uniform within q-group
            float alpha = EXP2(m_s - rmax);
            m_s = rmax;
            l_s *= alpha;
        }
        if (__any(trig)) {                           // rare after warm-up
            // o_acc rows are q = lg4+e; alpha state lives in lane (q) of group 0
            float al = trig ? EXP2(0.0f) : 1.0f;     // placeholder to keep alpha live
            (void)al;
            float a0 = __shfl(trig ? (m_s, 1.0f) : 1.0f, 0);  // dummy; replaced below
            (void)a0;
        }
        // NOTE: recompute alpha per output row via shfl of (m_old - m_new)?
        // Simpler correct path: broadcast per-q alpha value.
        {
            // alpha_q = 1 if no trigger for q, else exp2(m_old - m_new).
            // We stored neither m_old; instead carry alpha explicitly:
        }
        // ---- P = exp2(S - m), packed writes; l partial per lane ----
        float lsum;
        {
            float p00 = EXP2(s_acc[0][0] - m_s), p01 = EXP2(s_acc[0][1] - m_s);
            float p02 = EXP2(s_acc[0][2] - m_s), p03 = EXP2(s_acc[0][3] - m_s);
            float p10 = EXP2(s_acc[1][0] - m_s), p11 = EXP2(s_acc[1][1] - m_s);
            float p12 = EXP2(s_acc[1][2] - m_s), p13 = EXP2(s_acc[1][3] - m_s);
            float p20 = EXP2(s_acc[2][0] - m_s), p21 = EXP2(s_acc[2][1] - m_s);
            float p22 = EXP2(s_acc[2][2] - m_s), p23 = EXP2(s_acc[2][3] - m_s);
            float p30 = EXP2(s_acc[3][0] - m_s), p31 = EXP2(s_acc[3][1] - m_s);
            float p32 = EXP2(s_acc[3][2] - m_s), p33 = EXP2(s_acc[3][3] - m_s);
            lsum = ((p00 + p01) + (p02 + p03)) + ((p10 + p11) + (p12 + p13))
                 + ((p20 + p21) + (p22 + p23)) + ((p30 + p31) + (p32 + p33));
            uint2v w;
            short* prow = &Pl[wv][l15][lg4];
            w[0] = pkbf(p00, p01); w[1] = pkbf(p02, p03);
            *(uint2v*)(prow)      = w;
            w[0] = pkbf(p10, p11); w[1] = pkbf(p12, p13);
            *(uint2v*)(prow + 16) = w;
            w[0] = pkbf(p20, p21); w[1] = pkbf(p22, p23);
            *(uint2v*)(prow + 32) = w;
            w[0] = pkbf(p30, p31); w[1] = pkbf(p32, p33);
            *(uint2v*)(prow + 48) = w;
        }
        l_s += lsum;

        // ---- o_acc rescale (rare path) ----
        if (__any(trig)) {
            float alpha = trig ? EXP2((m_s == rmax ? 0.0f : 0.0f)) : 1.0f; (void)alpha;
        }
        // Correct rescale: carry explicit alpha from the trig block.
        // (computed below via a second pass kept branch-free)
        {
            // recompute alpha exactly as in trig block
            // alpha = exp2(m_old - m_new); we saved neither, so do it inline:
        }

        // wave-local LDS RAW: wait for this wave's ds_writes
        asm volatile("s_waitcnt lgkmcnt(0)" ::: "memory");

        // ---- O += P V ----
        const short8 p0 = *(const short8*)&Pl[wv][l15][dofs];
        const short8 p1 = *(const short8*)&Pl[wv][l15][dofs + 32];
        __builtin_amdgcn_s_setprio(1);
        #pragma unroll
        for (int dt = 0; dt < 4; ++dt) {
            const short8 v0 = *(const short8*)&Vt_lds[buf][dt * 16 + l15][dofs];
            const short8 v1 = *(const short8*)&Vt_lds[buf][dt * 16 + l15][dofs + 32];
            o_acc[dt] = __builtin_amdgcn_mfma_f32_16x16x32_bf16(p0, v0, o_acc[dt], 0, 0, 0);
            o_acc[dt] = __builtin_amdgcn_mfma_f32_16x16x32_bf16(p1, v1, o_acc[dt], 0, 0, 0);
        }
        __builtin_amdgcn_s_setprio(0);
    }

    // ---- finalize ----
    l_s += __shfl_xor(l_s, 16);
    l_s += __shfl_xor(l_s, 32);
    const float linv = 1.0f / l_s;
    #pragma unroll
    for (int e = 0; e < 4; ++e) {
        const float li = __shfl(linv, lg4 + e);
        const int row = qbase + wv * 16 + lg4 + e;
        #pragma unroll
        for (int dt = 0; dt < 4; ++dt)
            Op[(size_t)row * HD + dt * 16 + l15] = o_acc[dt][e] * li;
    }
}

// The alpha-rescale path above was getting convoluted; provide the clean,
// correct version used for the launch (v7b): identical but with explicit
// alpha tracked and o_acc rescaled before PV.

__global__ __launch_bounds__(256, 4)
void fa_fwd_v7b(const float* __restrict__ Q, const short* __restrict__ Kg,
                const short* __restrict__ Vtg, float* __restrict__ O)
{
    const int tid  = threadIdx.x;
    const int lane = tid & 63;
    const int wv   = tid >> 6;
    const int l15  = lane & 15;
    const int lg   = lane >> 4;
    const int lg4  = lg * 4;
    const int dofs = lg * 8;

    const int bh = blockIdx.x & (NBH - 1);
    const int qi = (NQT - 1) - (blockIdx.x >> 5);
    const int qbase = qi * QBLK;

    const float* Qp = Q   + (size_t)bh * SEQ * HD;
    const short* Kp = Kg  + (size_t)bh * SEQ * HD;
    const short* Vp = Vtg + (size_t)bh * HD * SEQ;
    float*       Op = O   + (size_t)bh * SEQ * HD;

    __shared__ __align__(16) short K_lds[2][KVBLK][LDK];
    __shared__ __align__(16) short Vt_lds[2][HD][LDK];
    __shared__ __align__(16) short Pl[4][16][LDK];

    const int r0 = tid >> 3,         j0 = tid & 7;
    const int r1 = (tid + 256) >> 3, j1 = tid & 7;
    const int kg0 = r0 * HD + j0 * 8, kg1 = r1 * HD + j1 * 8;
    const int vg0 = r0 * SEQ + j0 * 8, vg1 = r1 * SEQ + j1 * 8;

    short8 qfrag[2];
    {
        const float* src = Qp + (size_t)(qbase + wv * 16 + l15) * HD + dofs;
        union { unsigned u[4]; short8 s; } cv;
        float4 f0 = *(const float4*)(src);
        float4 f1 = *(const float4*)(src + 4);
        cv.u[0] = pkbf(f0.x * QSC, f0.y * QSC); cv.u[1] = pkbf(f0.z * QSC, f0.w * QSC);
        cv.u[2] = pkbf(f1.x * QSC, f1.y * QSC); cv.u[3] = pkbf(f1.z * QSC, f1.w * QSC);
        qfrag[0] = cv.s;
        f0 = *(const float4*)(src + 32);
        f1 = *(const float4*)(src + 36);
        cv.u[0] = pkbf(f0.x * QSC, f0.y * QSC); cv.u[1] = pkbf(f0.z * QSC, f0.w * QSC);
        cv.u[2] = pkbf(f1.x * QSC, f1.y * QSC); cv.u[3] = pkbf(f1.z * QSC, f1.w * QSC);
        qfrag[1] = cv.s;
    }

    short8 krA = *(const short8*)(Kp + kg0);
    short8 krB = *(const short8*)(Kp + kg1);
    short8 vrA = *(const short8*)(Vp + vg0);
    short8 vrB = *(const short8*)(Vp + vg1);

    floatx4 o_acc[4];
    #pragma unroll
    for (int dt = 0; dt < 4; ++dt)
        #pragma unroll
        for (int e = 0; e < 4; ++e) o_acc[dt][e] = 0.0f;
    float m_s = -1e30f, l_s = 0.0f;

    for (int t = 0; t <= qi; ++t) {
        const int buf = t & 1;
        *(short8*)&K_lds[buf][r0][j0 * 8]  = krA;
        *(short8*)&K_lds[buf][r1][j1 * 8]  = krB;
        *(short8*)&Vt_lds[buf][r0][j0 * 8] = vrA;
        *(short8*)&Vt_lds[buf][r1][j1 * 8] = vrB;
        __syncthreads();

        if (t < qi) {
            const short* ks = Kp + (size_t)(t + 1) * KVBLK * HD;
            const short* vs = Vp + (t + 1) * KVBLK;
            krA = *(const short8*)(ks + kg0);
            krB = *(const short8*)(ks + kg1);
            vrA = *(const short8*)(vs + vg0);
            vrB = *(const short8*)(vs + vg1);
        }

        floatx4 s_acc[4];
        __builtin_amdgcn_s_setprio(1);
        #pragma unroll
        for (int n = 0; n < 4; ++n) {
            const short8 k0 = *(const short8*)&K_lds[buf][n * 16 + l15][dofs];
            const short8 k1 = *(const short8*)&K_lds[buf][n * 16 + l15][dofs + 32];
            floatx4 acc = {0.0f, 0.0f, 0.0f, 0.0f};
            acc = __builtin_amdgcn_mfma_f32_16x16x32_bf16(k0, qfrag[0], acc, 0, 0, 0);
            acc = __builtin_amdgcn_mfma_f32_16x16x32_bf16(k1, qfrag[1], acc, 0, 0, 0);
            s_acc[n] = acc;
        }
        __builtin_amdgcn_s_setprio(0);

        if (t == qi) {
            const int qlocal = wv * 16 + l15;
            #pragma unroll
            for (int n = 0; n < 4; ++n)
                #pragma unroll
                for (int r = 0; r < 4; ++r)
                    if (n * 16 + lg4 + r > qlocal) s_acc[n][r] = -1e30f;
        }

        float t0 = fmaxf(fmaxf(s_acc[0][0], s_acc[0][1]), fmaxf(s_acc[0][2], s_acc[0][3]));
        float t1 = fmaxf(fmaxf(s_acc[1][0], s_acc[1][1]), fmaxf(s_acc[1][2], s_acc[1][3]));
        float t2 = fmaxf(fmaxf(s_acc[2][0], s_acc[2][1]), fmaxf(s_acc[2][2], s_acc[2][3]));
        float t3 = fmaxf(fmaxf(s_acc[3][0], s_acc[3][1]), fmaxf(s_acc[3][2], s_acc[3][3]));
        float rmax = fmaxf(fmaxf(t0, t1), fmaxf(t2, t3));
        rmax = fmaxf(rmax, __shfl_xor(rmax, 16));
        rmax = fmaxf(rmax, __shfl_xor(rmax, 32));

        const bool trig = rmax > m_s + THR;
        float alpha = 1.0f;
        if (trig) {
            alpha = EXP2(m_s - rmax);
            m_s = rmax;
            l_s *= alpha;
        }
        if (__any(trig)) {
            // o_acc row e is q=lg4+e; its alpha lives in lane (lg4+e) of group 0
            float a0 = __shfl(alpha, lg4 + 0);
            float a1 = __shfl(alpha, lg4 + 1);
            float a2 = __shfl(alpha, lg4 + 2);
            float a3 = __shfl(alpha, lg4 + 3);
            #pragma unroll
            for (int dt = 0; dt < 4; ++dt) {
                o_acc[dt][0] *= a0; o_acc[dt][1] *= a1;
                o_acc[dt][2] *= a2; o_acc[dt][3] *= a3;
            }
        }

        float lsum;
        {
            float p00 = EXP2(s_acc[0][0] - m_s), p01 = EXP2(s_acc[0][1] - m_s);
            float p02 = EXP2(s_acc[0][2] - m_s), p03 = EXP2(s_acc[0][3] - m_s);
            float p10 = EXP2(s_acc[1][0] - m_s), p11 = EXP2(s_acc[1][1] - m_s);
            float p12 = EXP2(s_acc[1][2] - m_s), p13 = EXP2(s_acc[1][3] - m_s);
            float p20 = EXP2(s_acc[2][0] - m_s), p21 = EXP2(s_acc[2][1] - m_s);
            float p22 = EXP2(s_acc[2][2] - m_s), p23 = EXP2(s_acc[2][3] - m_s);
            float p30 = EXP2(s_acc[3][0] - m_s), p31 = EXP2(s_acc[3][1] - m_s);
            float p32 = EXP2(s_acc[3][2] - m_s), p33 = EXP2(s_acc[3][3] - m_s);
            lsum = ((p00 + p01) + (p02 + p03)) + ((p10 + p11) + (p12 + p13))
                 + ((p20 + p21) + (p22 + p23)) + ((p30 + p31) + (p32 + p33));
            uint2v w;
            short* prow = &Pl[wv][l15][lg4];
            w[0] = pkbf(p00, p01); w[1] = pkbf(p02, p03);
            *(uint2v*)(prow)      = w;
            w[0] = pkbf(p10, p11); w[1] = pkbf(p12, p13);
            *(uint2v*)(prow + 16) = w;
            w[0] = pkbf(p20, p21); w[1] = pkbf(p22, p23);
            *(uint2v*)(prow + 32) = w;
            w[0] = pkbf(p30, p31); w[1] = pkbf(p32, p33);
            *(uint2v*)(prow + 48) = w;
        }
        l_s += lsum;

        asm volatile("s_waitcnt lgkmcnt(0)" ::: "memory");

        const short8 p0 = *(const short8*)&Pl[wv][l15][dofs];
        const short8 p1 = *(const short8*)&Pl[wv][l15][dofs + 32];
        __builtin_amdgcn_s_setprio(1);
        #pragma unroll
        for (int dt = 0; dt < 4; ++dt) {
            const short8 v0 = *(const short8*)&Vt_lds[buf][dt * 16 + l15][dofs];
            const short8 v1 = *(const short8*)&Vt_lds[buf][dt * 16 + l15][dofs + 32];
            o_acc[dt] = __builtin_amdgcn_mfma_f32_16x16x32_bf16(p0, v0, o_acc[dt], 0, 0, 0);
            o_acc[dt] = __builtin_amdgcn_mfma_f32_16x16x32_bf16(p1, v1, o_acc[dt], 0, 0, 0);
        }
        __builtin_amdgcn_s_setprio(0);
    }

    l_s += __shfl_xor(l_s, 16);
    l_s += __shfl_xor(l_s, 32);
    const float linv = 1.0f / l_s;
    #pragma unroll
    for (int e = 0; e < 4; ++e) {
        const float li = __shfl(linv, lg4 + e);
        const int row = qbase + wv * 16 + lg4 + e;
        #pragma unroll
        for (int dt = 0; dt < 4; ++dt)
            Op[(size_t)row * HD + dt * 16 + l15] = o_acc[dt][e] * li;
    }
}

// ---------------- fallback (round-1 kernel, proven) if ws too small ----------------

__global__ __launch_bounds__(256, 2)
void fa_fwd_v1(const float* __restrict__ Q, const float* __restrict__ K,
               const float* __restrict__ V, float* __restrict__ O)
{
    const int tid  = threadIdx.x;
    const int lane = tid & 63;
    const int wv   = tid >> 6;
    const int l15  = lane & 15;
    const int lg   = lane >> 4;
    const int dofs = lg * 8;
    const int bh = blockIdx.x & (NBH - 1);
    const int qi = 31 - (blockIdx.x >> 5);
    const size_t base = (size_t)bh * SEQ * HD;
    const float* Qp = Q + base; const float* Kp = K + base;
    const float* Vp = V + base; float* Op = O + base;
    const int qbase = qi * 64;
    __shared__ __align__(16) short K_lds[64][72];
    __shared__ __align__(16) short Vt_lds[HD][72];
    __shared__ __align__(16) short P_lds[4][16][72];
    short8 qfrag[2];
    {
        const float* src = Qp + (size_t)(qbase + wv * 16 + l15) * HD + dofs;
        #pragma unroll
        for (int c = 0; c < 2; ++c) {
            float4 f0 = *(const float4*)(src + 32 * c);
            float4 f1 = *(const float4*)(src + 32 * c + 4);
            short8 tt;
            tt[0] = f2bf(f0.x * 0.125f); tt[1] = f2bf(f0.y * 0.125f);
            tt[2] = f2bf(f0.z * 0.125f); tt[3] = f2bf(f0.w * 0.125f);
            tt[4] = f2bf(f1.x * 0.125f); tt[5] = f2bf(f1.y * 0.125f);
            tt[6] = f2bf(f1.z * 0.125f); tt[7] = f2bf(f1.w * 0.125f);
            qfrag[c] = tt;
        }
    }
    floatx4 o_acc[4];
    #pragma unroll
    for (int dt = 0; dt < 4; ++dt)
        #pragma unroll
        for (int e = 0; e < 4; ++e) o_acc[dt][e] = 0.0f;
    float m_r[4], l_r[4];
    #pragma unroll
    for (int r = 0; r < 4; ++r) { m_r[r] = -1e30f; l_r[r] = 0.0f; }
    for (int t = 0; t <= qi; ++t) {
        __syncthreads();
        {
            const float4* ks = (const float4*)(Kp + (size_t)t * 64 * HD);
            const float4* vs = (const float4*)(Vp + (size_t)t * 64 * HD);
            #pragma unroll
            for (int j = 0; j < 4; ++j) {
                int idx = j * 256 + tid;
                int row = idx >> 4;
                int col = (idx & 15) << 2;
                float4 kf = ks[idx];
                K_lds[row][col + 0] = f2bf(kf.x); K_lds[row][col + 1] = f2bf(kf.y);
                K_lds[row][col + 2] = f2bf(kf.z); K_lds[row][col + 3] = f2bf(kf.w);
                float4 vf = vs[idx];
                Vt_lds[col + 0][row] = f2bf(vf.x); Vt_lds[col + 1][row] = f2bf(vf.y);
                Vt_lds[col + 2][row] = f2bf(vf.z); Vt_lds[col + 3][row] = f2bf(vf.w);
            }
        }
        __syncthreads();
        floatx4 s_acc[4];
        #pragma unroll
        for (int n = 0; n < 4; ++n) {
            const short8 k0 = *(const short8*)&K_lds[n * 16 + l15][dofs];
            const short8 k1 = *(const short8*)&K_lds[n * 16 + l15][dofs + 32];
            floatx4 acc = {0.0f, 0.0f, 0.0f, 0.0f};
            acc = __builtin_amdgcn_mfma_f32_16x16x32_bf16(qfrag[0], k0, acc, 0, 0, 0);
            acc = __builtin_amdgcn_mfma_f32_16x16x32_bf16(qfrag[1], k1, acc, 0, 0, 0);
            s_acc[n] = acc;
        }
        if (t == qi) {
            #pragma unroll
            for (int n = 0; n < 4; ++n)
                #pragma unroll
                for (int r = 0; r < 4; ++r) {
                    int qr = wv * 16 + lg * 4 + r;
                    int kc = n * 16 + l15;
                    if (kc > qr) s_acc[n][r] = -1e30f;
                }
        }
        #pragma unroll
        for (int r = 0; r < 4; ++r) {
            float rmax = fmaxf(fmaxf(s_acc[0][r], s_acc[1][r]),
                               fmaxf(s_acc[2][r], s_acc[3][r]));
            rmax = fmaxf(rmax, __shfl_xor(rmax, 1));
            rmax = fmaxf(rmax, __shfl_xor(rmax, 2));
            rmax = fmaxf(rmax, __shfl_xor(rmax, 4));
            rmax = fmaxf(rmax, __shfl_xor(rmax, 8));
            float mnew  = fmaxf(m_r[r], rmax);
            float alpha = __expf(m_r[r] - mnew);
            m_r[r] = mnew;
            l_r[r] *= alpha;
            #pragma unroll
            for (int dt = 0; dt < 4; ++dt) o_acc[dt][r] *= alpha;
            #pragma unroll
            for (int n = 0; n < 4; ++n) {
                float p = __expf(s_acc[n][r] - mnew);
                l_r[r] += p;
                P_lds[wv][lg * 4 + r][n * 16 + l15] = f2bf(p);
            }
        }
        asm volatile("s_waitcnt lgkmcnt(0)" ::: "memory");
        const short8 p0 = *(const short8*)&P_lds[wv][l15][dofs];
        const short8 p1 = *(const short8*)&P_lds[wv][l15][dofs + 32];
        #pragma unroll
        for (int dt = 0; dt < 4; ++dt) {
            const short8 v0 = *(const short8*)&Vt_lds[dt * 16 + l15][dofs];
            const short8 v1 = *(const short8*)&Vt_lds[dt * 16 + l15][dofs + 32];
            o_acc[dt] = __builtin_amdgcn_mfma_f32_16x16x32_bf16(p0, v0, o_acc[dt], 0, 0, 0);
            o_acc[dt] = __builtin_amdgcn_mfma_f32_16x16x32_bf16(p1, v1, o_acc[dt], 0, 0, 0);
        }
    }
    #pragma unroll
    for (int r = 0; r < 4; ++r) {
        float l = l_r[r];
        l += __shfl_xor(l, 1);
        l += __shfl_xor(l, 2);
        l += __shfl_xor(l, 4);
        l += __shfl_xor(l, 8);
        l_r[r] = 1.0f / l;
    }
    #pragma unroll
    for (int dt = 0; dt < 4; ++dt)
        #pragma unroll
        for (int r = 0; r < 4; ++r) {
            int row = qbase + wv * 16 + lg * 4 + r;
            Op[(size_t)row * HD + dt * 16 + l15] = o_acc[dt][r] * l_r[r];
        }
}

extern "C" void kernel_launch(void* const* d_in, const int* in_sizes, int n_in,
                              void* d_out, int out_size, void* d_ws, size_t ws_size,
                              hipStream_t stream) {
    const float* q = (const float*)d_in[0];
    const float* k = (const float*)d_in[1];
    const float* v = (const float*)d_in[2];
    float* o = (float*)d_out;
    (void)in_sizes; (void)n_in; (void)out_size;

    const size_t elems = (size_t)NBH * SEQ * HD;
    const size_t need  = 2 * elems * sizeof(short);
    if (ws_size >= need) {
        short* kb = (short*)d_ws;
        short* vt = kb + elems;
        conv_k_kernel<<<dim3(elems / (256 * 8)), dim3(256), 0, stream>>>(k, kb);
        trans_v_kernel<<<dim3(NBH * 32), dim3(256), 0, stream>>>(v, vt);
        fa_fwd_v7b<<<dim3(NBH * NQT), dim3(256), 0, stream>>>(q, kb, vt, o);
    } else {
        fa_fwd_v1<<<dim3(NBH * 32), dim3(256), 0, stream>>>(q, k, v, o);
    }
}